// Round 8
// baseline (134.776 us; speedup 1.0000x reference)
//
#include <hip/hip_runtime.h>
#include <math.h>
#include <float.h>

#define NN 8192

typedef __bf16 bf16x8 __attribute__((ext_vector_type(8)));
typedef __bf16 bf16x4 __attribute__((ext_vector_type(4)));
typedef float f32x4 __attribute__((ext_vector_type(4)));

constexpr float POS_R2 = 0.0375f * 0.0375f;
constexpr float NEG_R2 = 0.1f * 0.1f;
constexpr float EPSF = 1e-7f;
constexpr float PRC = POS_R2 - EPSF;  // pos:  d2p < PRC
constexpr float NRC = NEG_R2 - EPSF;  // neg:  d2p > NRC
constexpr float POS_TH = 0.1f;
constexpr float NEG_TH = 1.4f;
constexpr float BIG_NEG = -1.0e30f;  // masked-out sentinel for max
constexpr float BIG_POS = 1.0e30f;   // masked-out sentinel for min

// ws byte offsets
#define FT_OFF 0                      // bf16 [NN][32] tgt feats (64 B/row)
#define FS2_OFF (NN * 64)             // bf16 [NN][32] -2 * src feats
#define PSX_OFF (NN * 128)            // bf16 [NN][16] src pos ext (32 B/row)
#define PTX_OFF (NN * 160)            // bf16 [NN][16] tgt pos ext
#define PAD_OFF (NN * 192)            // 64 B zeros (quad 2/3 over-read zone)
#define FNS_OFF (NN * 192 + 64)       // f32 [NN] src feat |.|^2
#define NT4_OFF (FNS_OFF + NN * 4)    // f32 [NN][4] tgt feat |.|^2 broadcast x4
#define MAXB_OFF (NT4_OFF + NN * 16)
#define MINB_OFF (MAXB_OFF + NN * 4)
#define CNT_OFF (MINB_OFF + NN * 4)

// ---------------------------------------------------------------------------
// Phase 1: gather + transform + bf16 conversion + MFMA operand packing.
// 8 threads per correspondence; part p handles feat float4 chunk p.
// ---------------------------------------------------------------------------
__global__ __launch_bounds__(256) void hcl_prep(
    const float* __restrict__ src_pcd, const float* __restrict__ tgt_pcd,
    const float* __restrict__ src_feats, const float* __restrict__ tgt_feats,
    const int* __restrict__ corr, const float* __restrict__ rot,
    const float* __restrict__ trans, char* __restrict__ ws) {
  int t = blockIdx.x * 256 + threadIdx.x;  // 0..65535
  int i = t >> 3;
  int p = t & 7;
  int ci = corr[2 * i];
  int cj = corr[2 * i + 1];

  // ---- feats: chunk p (4 dims) ----
  float4 a = ((const float4*)(src_feats + (size_t)ci * 32))[p];
  float4 b = ((const float4*)(tgt_feats + (size_t)cj * 32))[p];
  __bf16 h0 = (__bf16)a.x, h1 = (__bf16)a.y, h2 = (__bf16)a.z, h3 = (__bf16)a.w;
  float f0 = (float)h0, f1 = (float)h1, f2 = (float)h2, f3 = (float)h3;
  float na = f0 * f0 + f1 * f1 + f2 * f2 + f3 * f3;
  bf16x4 osrc;
  osrc[0] = (__bf16)(-2.f * f0); osrc[1] = (__bf16)(-2.f * f1);
  osrc[2] = (__bf16)(-2.f * f2); osrc[3] = (__bf16)(-2.f * f3);
  __bf16 g0 = (__bf16)b.x, g1 = (__bf16)b.y, g2 = (__bf16)b.z, g3 = (__bf16)b.w;
  float e0 = (float)g0, e1 = (float)g1, e2 = (float)g2, e3 = (float)g3;
  float nb = e0 * e0 + e1 * e1 + e2 * e2 + e3 * e3;
  bf16x4 otgt;
  otgt[0] = g0; otgt[1] = g1; otgt[2] = g2; otgt[3] = g3;
  *(bf16x4*)(ws + FS2_OFF + (size_t)i * 64 + p * 8) = osrc;
  *(bf16x4*)(ws + FT_OFF + (size_t)i * 64 + p * 8) = otgt;

  // norm reduce across the 8 parts (adjacent lanes)
  na += __shfl_xor(na, 1, 8);
  na += __shfl_xor(na, 2, 8);
  na += __shfl_xor(na, 4, 8);
  nb += __shfl_xor(nb, 1, 8);
  nb += __shfl_xor(nb, 2, 8);
  nb += __shfl_xor(nb, 4, 8);

  __bf16 one = (__bf16)1.0f, zero = (__bf16)0.0f;

  if (p == 0) {
    ((float*)(ws + FNS_OFF))[i] = na;
    f32x4 nb4 = {nb, nb, nb, nb};  // C-operand broadcast for the dist kernel
    ((f32x4*)(ws + NT4_OFF))[i] = nb4;
    ((unsigned int*)(ws + MAXB_OFF))[i] = 0u;           // max sentinel (clamped >= 0)
    ((unsigned int*)(ws + MINB_OFF))[i] = 0x7F7FFFFFu;  // FLT_MAX bits
  } else if (p == 3) {
    if (i == 0) {  // zero the quad-2/3 over-read pad + the ticket counter
      f32x4 z = {0.f, 0.f, 0.f, 0.f};
      ((f32x4*)(ws + PAD_OFF))[0] = z;
      ((f32x4*)(ws + PAD_OFF))[1] = z;
      ((f32x4*)(ws + PAD_OFF))[2] = z;
      ((f32x4*)(ws + PAD_OFF))[3] = z;
      *(unsigned int*)(ws + CNT_OFF) = 0u;
    }
  } else if (p == 1) {
    // src pos-ext (16 slots): [ah(3), ah(3), al(3), sah, sal, 1, 1, 0,0,0]
    float r00 = rot[0], r01 = rot[1], r02 = rot[2];
    float r10 = rot[3], r11 = rot[4], r12 = rot[5];
    float r20 = rot[6], r21 = rot[7], r22 = rot[8];
    float t0 = trans[0], t1 = trans[1], t2 = trans[2];
    float px = src_pcd[ci * 3 + 0], py = src_pcd[ci * 3 + 1], pz = src_pcd[ci * 3 + 2];
    float qx = r00 * px + r01 * py + r02 * pz + t0;
    float qy = r10 * px + r11 * py + r12 * pz + t1;
    float qz = r20 * px + r21 * py + r22 * pz + t2;
    float sa = qx * qx + qy * qy + qz * qz;
    __bf16 qhx = (__bf16)qx, qhy = (__bf16)qy, qhz = (__bf16)qz;
    __bf16 qlx = (__bf16)(qx - (float)qhx);
    __bf16 qly = (__bf16)(qy - (float)qhy);
    __bf16 qlz = (__bf16)(qz - (float)qhz);
    __bf16 sah = (__bf16)sa;
    __bf16 sal = (__bf16)(sa - (float)sah);
    bf16x8 v0, v1;
    v0[0] = qhx; v0[1] = qhy; v0[2] = qhz; v0[3] = qhx; v0[4] = qhy; v0[5] = qhz;
    v0[6] = qlx; v0[7] = qly;
    v1[0] = qlz; v1[1] = sah; v1[2] = sal; v1[3] = one; v1[4] = one;
    v1[5] = zero; v1[6] = zero; v1[7] = zero;
    bf16x8* o = (bf16x8*)(ws + PSX_OFF + (size_t)i * 32);
    o[0] = v0;
    o[1] = v1;
  } else if (p == 2) {
    // tgt pos-ext (16 slots): [-2bh(3), -2bl(3), -2bh(3), 1, 1, sbh, sbl, 0,0,0]
    float ux = tgt_pcd[cj * 3 + 0], uy = tgt_pcd[cj * 3 + 1], uz = tgt_pcd[cj * 3 + 2];
    float sb = ux * ux + uy * uy + uz * uz;
    __bf16 uhx = (__bf16)ux, uhy = (__bf16)uy, uhz = (__bf16)uz;
    __bf16 ulx = (__bf16)(ux - (float)uhx);
    __bf16 uly = (__bf16)(uy - (float)uhy);
    __bf16 ulz = (__bf16)(uz - (float)uhz);
    __bf16 sbh = (__bf16)sb;
    __bf16 sbl = (__bf16)(sb - (float)sbh);
    __bf16 m2hx = (__bf16)(-2.f * (float)uhx), m2hy = (__bf16)(-2.f * (float)uhy),
           m2hz = (__bf16)(-2.f * (float)uhz);
    __bf16 m2lx = (__bf16)(-2.f * (float)ulx), m2ly = (__bf16)(-2.f * (float)uly),
           m2lz = (__bf16)(-2.f * (float)ulz);
    bf16x8 w0, w1;
    w0[0] = m2hx; w0[1] = m2hy; w0[2] = m2hz; w0[3] = m2lx; w0[4] = m2ly; w0[5] = m2lz;
    w0[6] = m2hx; w0[7] = m2hy;
    w1[0] = m2hz; w1[1] = one; w1[2] = one; w1[3] = sbh; w1[4] = sbl;
    w1[5] = zero; w1[6] = zero; w1[7] = zero;
    bf16x8* o = (bf16x8*)(ws + PTX_OFF + (size_t)i * 32);
    o[0] = w0;
    o[1] = w1;
  }
}

// ---------------------------------------------------------------------------
// Phase 2 (+fused loss): MFMA pairwise distances + masked row max/min.
// Proven R2-style fully-coalesced 16x16x32 layout (VGPR ~60). Per step:
// 3 b128 loads + 4 MFMA + 48 VALU. fb rides in the MFMA C-operand (NT4
// broadcast); fa is added after the lane reduction (commutes with max/min).
// Grid (32 j-chunks, 64 row-blocks) = 2048 blocks = 8 blocks/CU; with
// VGPR <= 64 that is 8 waves/SIMD — 2x the TLP of every prior attempt
// (R2/R3 ran at Occupancy ~31%; latency-bound). No launch-bounds cap
// tighter than (256,4): R6 showed a tight cap converts to spills.
// Last block (ticket) computes the final loss: one ACQ_REL ticket add by
// tid0 after __syncthreads (barrier drains each wave's vmcnt, so all
// atomics are complete) — no per-thread threadfence (R4's 70 us mistake).
// ---------------------------------------------------------------------------
__global__ __launch_bounds__(256, 4) void hcl_dist(char* __restrict__ ws,
                                                   float* __restrict__ out) {
  const int lane = threadIdx.x & 63;
  const int wv = threadIdx.x >> 6;
  const int quad = lane >> 4;
  const int n = lane & 15;
  const int i0 = blockIdx.y * 128 + wv * 32;
  const int j0 = blockIdx.x * 256;

  // ---- A side (one-time) ----
  const bf16x8 afeat0 = *(const bf16x8*)(ws + FS2_OFF + (size_t)(i0 + n) * 64 + quad * 16);
  const bf16x8 afeat1 =
      *(const bf16x8*)(ws + FS2_OFF + (size_t)(i0 + 16 + n) * 64 + quad * 16);
  bf16x8 apos0 = {}, apos1 = {};
  if (quad < 2) {  // K slots 0..15 in quads 0,1; quads 2,3 stay zero
    apos0 = *(const bf16x8*)(ws + PSX_OFF + (size_t)(i0 + n) * 32 + quad * 16);
    apos1 = *(const bf16x8*)(ws + PSX_OFF + (size_t)(i0 + 16 + n) * 32 + quad * 16);
  }

  float maxv[8], minv[8];
#pragma unroll
  for (int r = 0; r < 8; ++r) {
    maxv[r] = BIG_NEG;
    minv[r] = BIG_POS;
  }

  const char* pF = ws + FT_OFF + (size_t)(j0 + n) * 64 + quad * 16;
  const char* pP = ws + PTX_OFF + (size_t)(j0 + n) * 32 + quad * 16;
  const char* pN = ws + NT4_OFF + (size_t)(j0 + n) * 16;

#pragma unroll 2
  for (int s = 0; s < 16; ++s) {
    const bf16x8 bfeat = *(const bf16x8*)(pF + s * 1024);
    const bf16x8 bpos = *(const bf16x8*)(pP + s * 512);  // quads 2,3: inert garbage
    const f32x4 cb = *(const f32x4*)(pN + s * 256);      // {fb,fb,fb,fb}
    f32x4 z = {0.f, 0.f, 0.f, 0.f};

    // d = fb - 2*dot(feat); u = d2p (both pos norms inside the ext rows)
    f32x4 d0 = __builtin_amdgcn_mfma_f32_16x16x32_bf16(afeat0, bfeat, cb, 0, 0, 0);
    f32x4 d1 = __builtin_amdgcn_mfma_f32_16x16x32_bf16(afeat1, bfeat, cb, 0, 0, 0);
    f32x4 u0 = __builtin_amdgcn_mfma_f32_16x16x32_bf16(apos0, bpos, z, 0, 0, 0);
    f32x4 u1 = __builtin_amdgcn_mfma_f32_16x16x32_bf16(apos1, bpos, z, 0, 0, 0);

#pragma unroll
    for (int r = 0; r < 4; ++r) {
      maxv[r] = fmaxf(maxv[r], (u0[r] < PRC) ? d0[r] : BIG_NEG);
      minv[r] = fminf(minv[r], (u0[r] > NRC) ? d0[r] : BIG_POS);
      maxv[4 + r] = fmaxf(maxv[4 + r], (u1[r] < PRC) ? d1[r] : BIG_NEG);
      minv[4 + r] = fminf(minv[4 + r], (u1[r] > NRC) ? d1[r] : BIG_POS);
    }
  }

  // ---- reduce over 16 col-lanes per quad, add fa, atomic-merge per row ----
  unsigned int* maxb = (unsigned int*)(ws + MAXB_OFF);
  unsigned int* minb = (unsigned int*)(ws + MINB_OFF);
#pragma unroll
  for (int r = 0; r < 8; ++r) {
    float mx = maxv[r], mn = minv[r];
#pragma unroll
    for (int sh = 1; sh <= 8; sh <<= 1) {
      mx = fmaxf(mx, __shfl_xor(mx, sh, 16));
      mn = fminf(mn, __shfl_xor(mn, sh, 16));
    }
    if (n == 0) {
      int row = i0 + (r < 4 ? 0 : 16) + quad * 4 + (r & 3);
      float fa = *(const float*)(ws + FNS_OFF + (size_t)row * 4);
      atomicMax(maxb + row, __float_as_uint(fmaxf(fa + mx, 0.f)));
      atomicMin(minb + row, __float_as_uint(fmaxf(fa + mn, 0.f)));
    }
  }

  // ---- fused loss: ticket; last of 2048 blocks reduces ----
  __shared__ unsigned int s_ticket;
  __shared__ float red[8];
  __syncthreads();  // drains each wave's vmcnt -> all atomics above complete
  if (threadIdx.x == 0) {
    s_ticket = __hip_atomic_fetch_add((unsigned int*)(ws + CNT_OFF), 1u,
                                      __ATOMIC_ACQ_REL, __HIP_MEMORY_SCOPE_AGENT);
  }
  __syncthreads();
  if (s_ticket == 32 * 64 - 1) {
    float sp = 0.f, sn = 0.f;
#pragma unroll
    for (int k = 0; k < 32; ++k) {
      int i = threadIdx.x + 256 * k;
      float mx = __uint_as_float(
          __hip_atomic_load(maxb + i, __ATOMIC_RELAXED, __HIP_MEMORY_SCOPE_AGENT));
      float mn = __uint_as_float(
          __hip_atomic_load(minb + i, __ATOMIC_RELAXED, __HIP_MEMORY_SCOPE_AGENT));
      sp += fmaxf(sqrtf(mx + EPSF) - POS_TH, 0.f);
      sn += fmaxf(NEG_TH - sqrtf(mn + EPSF), 0.f);
    }
#pragma unroll
    for (int sh = 32; sh >= 1; sh >>= 1) {
      sp += __shfl_down(sp, sh, 64);
      sn += __shfl_down(sn, sh, 64);
    }
    if (lane == 0) {
      red[wv] = sp;
      red[4 + wv] = sn;
    }
    __syncthreads();
    if (threadIdx.x == 0) {
      float tsp = red[0] + red[1] + red[2] + red[3];
      float tsn = red[4] + red[5] + red[6] + red[7];
      out[0] = (tsp + tsn) * (1.0f / NN);
    }
  }
}

// ---------------------------------------------------------------------------
extern "C" void kernel_launch(void* const* d_in, const int* in_sizes, int n_in,
                              void* d_out, int out_size, void* d_ws, size_t ws_size,
                              hipStream_t stream) {
  const float* src_pcd = (const float*)d_in[0];
  const float* tgt_pcd = (const float*)d_in[1];
  const float* src_feats = (const float*)d_in[2];
  const float* tgt_feats = (const float*)d_in[3];
  const int* corr = (const int*)d_in[4];
  const float* rot = (const float*)d_in[5];
  const float* trans = (const float*)d_in[6];
  float* out = (float*)d_out;
  char* ws = (char*)d_ws;

  hcl_prep<<<NN * 8 / 256, 256, 0, stream>>>(src_pcd, tgt_pcd, src_feats, tgt_feats, corr,
                                             rot, trans, ws);
  hcl_dist<<<dim3(32, 64), 256, 0, stream>>>(ws, out);
}